// Round 26
// baseline (336.221 us; speedup 1.0000x reference)
//
#include <hip/hip_runtime.h>
#include <hip/hip_bf16.h>

#define NNODES 50000
#define NEDGES 800000
#define IN_DIM 256
#define HID_DIM 256
#define OUT_DIM 64
#define NHEADS 4
#define ATT_DIM 129
#define PDIM 128   // main P row length; j=128 tail in separate arrays
#define PJROWS 144 // A1T padded rows (129 -> 144, zero-filled)
#define MAXD 64    // padded CSR slots per row (P(deg>64) ~ 1e-13, clamped)

#define XS_LD 264  // LDS row stride (u16); 528B: %16==0
#define FS_LD 72   // LDS row stride (u16) for 64-wide feats tile; 144B = 9*16
#define PS_LD 144  // LDS row stride (bytes) for fp8 P tiles; 144 = 9*16

#define LOG2E 1.44269504088896340736f

typedef unsigned short u16;
typedef unsigned char u8;
typedef unsigned int u32;
typedef __attribute__((ext_vector_type(8))) short bf16x8;
typedef __attribute__((ext_vector_type(4))) float f32x4;
typedef __attribute__((ext_vector_type(2))) float f32x2;
typedef __attribute__((ext_vector_type(2))) _Float16 h16x2;
typedef __fp16 hh2 __attribute__((ext_vector_type(2)));

__device__ __forceinline__ u16 f2bf(float f) {
  union { __hip_bfloat16 b; u16 u; } v;
  v.b = __float2bfloat16(f);
  return v.u;
}
__device__ __forceinline__ float bf2f(u16 b) {
  return __uint_as_float(((u32)b) << 16);
}
__device__ __forceinline__ h16x2 u2h2(u32 u) {
  union { u32 u; h16x2 h; } v; v.u = u; return v.h;
}
__device__ __forceinline__ u32 h2u(h16x2 h) {
  union { h16x2 h; u32 u; } v; v.h = h; return v.u;
}
__device__ __forceinline__ h16x2 pkrtz(float a, float b) {
  return __builtin_bit_cast(h16x2, __builtin_amdgcn_cvt_pkrtz(a, b));
}
__device__ __forceinline__ u32 cvt_pk_bf16(float a, float b) {
  u32 r;
  asm("v_cvt_pk_bf16_f32 %0, %1, %2" : "=v"(r) : "v"(a), "v"(b));
  return r;
}

// 8-lane xor-sum via DPP: xor1 (quad_perm 0xB1), xor2 (quad_perm 0x4E), then
// half-row mirror (0x141).
__device__ __forceinline__ float dpp_sum8(float x) {
  int v;
  v = __builtin_amdgcn_update_dpp(0, __float_as_int(x), 0xB1, 0xF, 0xF, true);
  x += __int_as_float(v);
  v = __builtin_amdgcn_update_dpp(0, __float_as_int(x), 0x4E, 0xF, 0xF, true);
  x += __int_as_float(v);
  v = __builtin_amdgcn_update_dpp(0, __float_as_int(x), 0x141, 0xF, 0xF, true);
  x += __int_as_float(v);
  return x;
}

// ---------------------------------------------------------------------------
// prep: weight transposes, edge const tables, padded-CSR fill. ab1 is folded
// into Pr8/Prt at mlp time, so no thB1 table is needed by edge.
// ---------------------------------------------------------------------------
__global__ __launch_bounds__(256) void prep_kernel(
    const int* __restrict__ idx, const float* __restrict__ elem,
    const float* __restrict__ W1, const float* __restrict__ W2,
    const float* __restrict__ A1, const float* __restrict__ ab1,
    const float* __restrict__ A2, const float* __restrict__ ab2,
    u16* __restrict__ W1T, u16* __restrict__ W2T,
    u16* __restrict__ A1Tr, u16* __restrict__ A1Tc,
    uint4* __restrict__ thE, uint4* __restrict__ thA2,
    float4* __restrict__ th_tail, u32* __restrict__ cnt, u32* __restrict__ ce)
{
  int id = blockIdx.x * 256 + threadIdx.x;
  if (id < NEDGES) {  // CSR fill
    int r = idx[id];
    u32 p = atomicAdd(&cnt[r], 1u);
    if (p < MAXD)
      ce[r * MAXD + p] = ((u32)f2bf(elem[id]) << 16) | (u32)idx[NEDGES + id];
  }
  if (id < NHEADS * 256 * 256) {
    int h = id >> 16, j = (id >> 8) & 255, k = id & 255;
    W1T[id] = f2bf(W1[(size_t)h * 65536 + k * 256 + j]);
  }
  if (id < NHEADS * 64 * 256) {
    int h = id >> 14, d = (id >> 8) & 63, j = id & 255;
    W2T[id] = f2bf(W2[(size_t)h * 16384 + j * 64 + d]);
  }
  if (id < NHEADS * PJROWS * 64) {
    int h = id / (PJROWS * 64);
    int rem = id % (PJROWS * 64);
    int j = rem >> 6, d = rem & 63;
    A1Tr[id] = (j < ATT_DIM) ? f2bf(A1[(size_t)h * 16641 + d * ATT_DIM + j]) : (u16)0;
    A1Tc[id] = (j < ATT_DIM) ? f2bf(A1[(size_t)h * 16641 + (64 + d) * ATT_DIM + j]) : (u16)0;
  }
  if (id < NHEADS * 16) {
    int h = id >> 4, m = id & 15;
    const float* Erow = A1 + (size_t)h * 16641 + (size_t)128 * ATT_DIM;
    uint4 e, a;
    u32* ep = (u32*)&e; u32* ap = (u32*)&a;
#pragma unroll
    for (int p = 0; p < 4; ++p) {
      int j = m * 8 + 2 * p;
      ep[p] = h2u(pkrtz(Erow[j], Erow[j + 1]));
      ap[p] = h2u(pkrtz(A2[h * ATT_DIM + j] * LOG2E, A2[h * ATT_DIM + j + 1] * LOG2E));
    }
    thE[id] = e; thA2[id] = a;
  }
  if (id < NHEADS) {
    const float* Erow = A1 + (size_t)id * 16641 + (size_t)128 * ATT_DIM;
    th_tail[id] = make_float4(Erow[128], 0.f,
                              A2[id * ATT_DIM + 128] * LOG2E, ab2[id] * LOG2E);
  }
}

// ---------------------------------------------------------------------------
// Fused MFMA node-MLP + projection; 64-node tiles, 2-head loop, 512 threads
// (8 waves; r25 measured win). Proj epilogue adds ab1[j] BEFORE quantizing Pr
// (the ab1-fold: edge then needs no bias table/adds).
// PF: [n](4h x {128B fp8 Pc | 128B bf16 feats}); Pr8: [h][n][128] fp8.
// ---------------------------------------------------------------------------
__global__ __launch_bounds__(512) void mlp_mfma_kernel(
    const float* __restrict__ x, const u16* __restrict__ W1T,
    const float* __restrict__ b1, const u16* __restrict__ W2T,
    const float* __restrict__ b2, const u16* __restrict__ A1Tr,
    const u16* __restrict__ A1Tc, const float* __restrict__ ab1,
    u8* __restrict__ PF, u8* __restrict__ Pr8,
    u16* __restrict__ Prt, u16* __restrict__ Pct)
{
  __shared__ u16 xs[64 * XS_LD];  // staged x tile (bf16), intact across heads
  __shared__ u16 hs[64 * XS_LD];  // hid tile; freed after L2, reused for P tiles
  __shared__ u16 fs[64 * FS_LD];  // feats tile (row = 144B = 9*16)
  u8* pc_s = (u8*)hs;             // [64][PS_LD] fp8 Pc tile (overlay)
  u8* pr_s = (u8*)hs + 64 * PS_LD;// [64][PS_LD] fp8 Pr tile (overlay)
  const int n0 = blockIdx.x * 64;
  const int t = threadIdx.x;
  const int wv = t >> 6;   // 0..7
  const int l = t & 63;
  const int lr = l & 15;
  const int lq = l >> 4;

  // ---- stage x tile fp32 -> bf16 (once for both heads) ----
#pragma unroll
  for (int q = 0; q < 8; ++q) {
    int fi = q * 512 + t;        // float4 units: 64 rows x 64
    int row = fi >> 6, c4 = fi & 63;
    int n = n0 + row;
    float4 v = make_float4(0.f, 0.f, 0.f, 0.f);
    if (n < NNODES) v = *(const float4*)(x + (size_t)n * IN_DIM + c4 * 4);
    ushort4 o;
    o.x = f2bf(v.x); o.y = f2bf(v.y); o.z = f2bf(v.z); o.w = f2bf(v.w);
    *(ushort4*)&xs[row * XS_LD + c4 * 4] = o;
  }
  __syncthreads();

  for (int hi = 0; hi < 2; ++hi) {
    const int h = (int)blockIdx.y + hi * 2;

    // ---- layer 1: C[j][node]; wave owns 32 j's (wv*32..+31) ----
    f32x4 acc[2][4];
#pragma unroll
    for (int ji = 0; ji < 2; ++ji)
#pragma unroll
      for (int ni = 0; ni < 4; ++ni) acc[ji][ni] = f32x4{0.f, 0.f, 0.f, 0.f};

    const u16* W1b = W1T + ((size_t)h * 256 + wv * 32) * 256;
#pragma unroll
    for (int kk = 0; kk < 8; ++kk) {
      const int ko = kk * 32 + lq * 8;
      bf16x8 w[2], xv[4];
#pragma unroll
      for (int ji = 0; ji < 2; ++ji)
        w[ji] = *(const bf16x8*)(W1b + (size_t)(ji * 16 + lr) * 256 + ko);
#pragma unroll
      for (int ni = 0; ni < 4; ++ni)
        xv[ni] = *(const bf16x8*)&xs[(ni * 16 + lr) * XS_LD + ko];
#pragma unroll
      for (int ji = 0; ji < 2; ++ji)
#pragma unroll
        for (int ni = 0; ni < 4; ++ni)
          acc[ji][ni] = __builtin_amdgcn_mfma_f32_16x16x32_bf16(w[ji], xv[ni], acc[ji][ni], 0, 0, 0);
    }
#pragma unroll
    for (int ji = 0; ji < 2; ++ji) {
      float4 bv = *(const float4*)(b1 + h * HID_DIM + wv * 32 + ji * 16 + lq * 4);
#pragma unroll
      for (int ni = 0; ni < 4; ++ni) {
        f32x4 v = acc[ji][ni];
        u32 lo = cvt_pk_bf16(fmaxf(v[0] + bv.x, 0.f), fmaxf(v[1] + bv.y, 0.f));
        u32 hi2 = cvt_pk_bf16(fmaxf(v[2] + bv.z, 0.f), fmaxf(v[3] + bv.w, 0.f));
        *(uint2*)&hs[(ni * 16 + lr) * XS_LD + wv * 32 + ji * 16 + lq * 4] = make_uint2(lo, hi2);
      }
    }
    __syncthreads();

    // ---- layer 2: C[d][node]; wave = (d-group wv&3, node-half wv>>2) ----
    {
      const int dg = wv & 3, nh = wv >> 2;
      f32x4 acc2[2];
#pragma unroll
      for (int ni = 0; ni < 2; ++ni) acc2[ni] = f32x4{0.f, 0.f, 0.f, 0.f};
      const u16* W2b = W2T + ((size_t)h * 64 + dg * 16) * 256;
#pragma unroll
      for (int kk = 0; kk < 8; ++kk) {
        const int ko = kk * 32 + lq * 8;
        bf16x8 wd = *(const bf16x8*)(W2b + (size_t)lr * 256 + ko);
#pragma unroll
        for (int ni = 0; ni < 2; ++ni) {
          bf16x8 hv = *(const bf16x8*)&hs[(nh * 32 + ni * 16 + lr) * XS_LD + ko];
          acc2[ni] = __builtin_amdgcn_mfma_f32_16x16x32_bf16(wd, hv, acc2[ni], 0, 0, 0);
        }
      }
      __syncthreads();  // all waves done reading hs (freed for pc_s/pr_s)
      float4 bv = *(const float4*)(b2 + h * OUT_DIM + dg * 16 + lq * 4);
      const int d0 = dg * 16 + lq * 4;
#pragma unroll
      for (int ni = 0; ni < 2; ++ni) {
        f32x4 v = acc2[ni];
        u32 lo = cvt_pk_bf16(v[0] + bv.x, v[1] + bv.y);
        u32 hi2 = cvt_pk_bf16(v[2] + bv.z, v[3] + bv.w);
        *(uint2*)&fs[(nh * 32 + ni * 16 + lr) * FS_LD + d0] = make_uint2(lo, hi2);
      }
    }
    __syncthreads();  // fs complete

    // ---- fused projection -> pc_s / pr_s (LDS); tails direct (tiny).
    //      Pr gets ab1[j] folded in BEFORE fp8 quantization (edge bias-free).
    for (int c = wv; c < 18; c += 8) {
      const int rc = c / 9;
      const int nf = c % 9;
      const u16* Ab = (rc ? A1Tc : A1Tr) + ((size_t)h * PJROWS + nf * 16) * 64;
      f32x4 acc3[4];
#pragma unroll
      for (int ni = 0; ni < 4; ++ni) acc3[ni] = f32x4{0.f, 0.f, 0.f, 0.f};
#pragma unroll
      for (int kk = 0; kk < 2; ++kk) {
        const int ko = kk * 32 + lq * 8;
        bf16x8 aj = *(const bf16x8*)(Ab + (size_t)lr * 64 + ko);
#pragma unroll
        for (int ni = 0; ni < 4; ++ni) {
          bf16x8 fv = *(const bf16x8*)&fs[(ni * 16 + lr) * FS_LD + ko];
          acc3[ni] = __builtin_amdgcn_mfma_f32_16x16x32_bf16(aj, fv, acc3[ni], 0, 0, 0);
        }
      }
      float4 abv = make_float4(0.f, 0.f, 0.f, 0.f);
      float abt = 0.f;
      if (rc == 0) {
        if (nf == 8) abt = ab1[h * ATT_DIM + 128];
        else         abv = *(const float4*)(ab1 + h * ATT_DIM + nf * 16 + lq * 4);
      }
#pragma unroll
      for (int ni = 0; ni < 4; ++ni) {
        const int node = ni * 16 + lr;
        int n = n0 + node;
        if (n >= NNODES) continue;
        if (nf == 8) {
          if (lq == 0) {  // j = 128 tail (bf16)
            if (rc == 0) Prt[(size_t)h * NNODES + n] = f2bf(acc3[ni][0] + abt);
            else         Pct[(size_t)n * NHEADS + h] = f2bf(acc3[ni][0]);
          }
        } else {
          const int j0 = nf * 16 + lq * 4;
          f32x4 v = acc3[ni];
          if (rc == 0) {
            u32 pk = __builtin_amdgcn_cvt_pk_fp8_f32(v[0] + abv.x, v[1] + abv.y, 0, false);
            pk = __builtin_amdgcn_cvt_pk_fp8_f32(v[2] + abv.z, v[3] + abv.w, pk, true);
            *(u32*)(pr_s + node * PS_LD + j0) = pk;
          } else {
            u32 pk = __builtin_amdgcn_cvt_pk_fp8_f32(v[0], v[1], 0, false);
            pk = __builtin_amdgcn_cvt_pk_fp8_f32(v[2], v[3], pk, true);
            *(u32*)(pc_s + node * PS_LD + j0) = pk;
          }
        }
      }
    }
    __syncthreads();  // P tiles complete

    // ---- coalesced store phase ----
    // PF: 64 nodes x 16 uint4 (256B contiguous per node = 2 full lines)
#pragma unroll
    for (int it = 0; it < 2; ++it) {
      int flat = it * 512 + t;
      int node = flat >> 4, sub = flat & 15;
      int n = n0 + node;
      if (n < NNODES) {
        uint4 v;
        if (sub < 8) v = *(const uint4*)(pc_s + node * PS_LD + sub * 16);
        else         v = *(const uint4*)((const u8*)&fs[node * FS_LD] + (sub - 8) * 16);
        *(uint4*)(PF + (size_t)n * 1024 + h * 256 + sub * 16) = v;
      }
    }
    // Pr8 tile: [h][n0..n0+64)[128] is one contiguous 8KB run (512 uint4)
    {
      int node = t >> 3, sub = t & 7;
      int n = n0 + node;
      if (n < NNODES) {
        uint4 v = *(const uint4*)(pr_s + node * PS_LD + sub * 16);
        *(uint4*)(Pr8 + ((size_t)h * NNODES + n) * PDIM + sub * 16) = v;
      }
    }
    __syncthreads();  // protect hs/fs reuse by next head
  }
}

// ---------------------------------------------------------------------------
// CSR edge aggregation (r22 structure — measured best): one (row, head) per
// wave; 8 groups of 8 lanes, 8 edges/iter; lane m covers j=16m..16m+15
// (uint4 fp8 Pc) and output dims 8m..8m+7 (uint4 bf16 feats). ab1 is folded
// into Pr8/Prt (no bias table/adds here). 3-level DPP reduce.
// ---------------------------------------------------------------------------
__global__ __launch_bounds__(256) void edge_csr_kernel(
    const u8* __restrict__ PF, const u8* __restrict__ Pr8,
    const u16* __restrict__ Prt, const u16* __restrict__ Pct,
    const u32* __restrict__ cnt, const u32* __restrict__ ce,
    const uint4* __restrict__ thE, const uint4* __restrict__ thA2,
    const float4* __restrict__ th_tail, float* __restrict__ out)
{
  const int r = blockIdx.x;
  const int h = threadIdx.x >> 6;
  const int l = threadIdx.x & 63;
  const int g = l >> 3;    // 8 groups, edge slot
  const int m = l & 7;     // lane-in-group: j = 16m..16m+15, dims 8m..8m+7

  const int deg = min((int)cnt[r], MAXD);
  if (deg == 0) {  // ref: pooled 0 / (0 + 1e-10) = 0
    if (g == 0) {
      float4 z = make_float4(0.f, 0.f, 0.f, 0.f);
      float* o = out + (size_t)r * (NHEADS * OUT_DIM) + h * OUT_DIM + m * 8;
      *(float4*)o = z; *(float4*)(o + 4) = z;
    }
    return;
  }

  // packed per-lane constants for j = 16m..16m+15 (Pr8 already includes ab1)
  h16x2 Ej2[8], a2v2[8], prb2[8];
  {
    uint4 pr8v = *(const uint4*)(Pr8 + ((size_t)h * NNODES + r) * PDIM + m * 16);
    const u32* pw = (const u32*)&pr8v;
#pragma unroll
    for (int half = 0; half < 2; ++half) {
      uint4 Eu = thE[h * 16 + 2 * m + half];
      uint4 Au = thA2[h * 16 + 2 * m + half];
      const u32* ep = (const u32*)&Eu;
      const u32* ap = (const u32*)&Au;
#pragma unroll
      for (int p = 0; p < 2; ++p) {
        u32 w8 = pw[half * 2 + p];
        f32x2 qa = __builtin_amdgcn_cvt_pk_f32_fp8((int)w8, false);
        f32x2 qb = __builtin_amdgcn_cvt_pk_f32_fp8((int)w8, true);
        int o = half * 4 + p * 2;
        Ej2[o]      = u2h2(ep[p * 2]);
        Ej2[o + 1]  = u2h2(ep[p * 2 + 1]);
        a2v2[o]     = u2h2(ap[p * 2]);
        a2v2[o + 1] = u2h2(ap[p * 2 + 1]);
        prb2[o]     = pkrtz(qa[0], qa[1]);
        prb2[o + 1] = pkrtz(qb[0], qb[1]);
      }
    }
  }
  const float4 tl = th_tail[h];
  float Et = 0.f, prtb = 0.f, a2t = 0.f;
  if (m == 0) {
    Et = tl.x;
    prtb = bf2f(Prt[(size_t)h * NNODES + r]);  // ab1[128] pre-folded
    a2t = tl.z;
  }
  const float ab2v = tl.w;
  const h16x2 zero2 = {(_Float16)0.f, (_Float16)0.f};
  const u8* PFh = PF + h * 256;

  const u32* cebase = ce + r * MAXD;

  float acc[8];
#pragma unroll
  for (int q = 0; q < 8; ++q) acc[q] = 0.f;
  float wsum = 0.f;

  for (int k0 = 0; k0 < deg; k0 += 8) {
    const int e0 = k0 + g;
    u32 cv = cebase[(e0 < deg) ? e0 : (deg - 1)];
    u32 coloff = (cv & 0xffffu) << 10;
    float el = __uint_as_float(cv & 0xffff0000u);

    uint4 pc = *(const uint4*)(PFh + coloff + m * 16);        // 16 fp8 Pc
    uint4 f4 = *(const uint4*)(PFh + coloff + 128 + m * 16);  // 8 bf16 feats
    float pctv = (m == 0) ? bf2f(Pct[(coloff >> 8) + h]) : 0.f;

    // tail j=128 (only m==0 lanes have nonzero constants)
    float tsum = fmaxf(fmaf(el, Et, prtb + pctv), 0.f) * a2t;

    const u32* pcw = (const u32*)&pc;
    const h16x2 el2 = pkrtz(el, el);
#pragma unroll
    for (int p = 0; p < 4; ++p) {
      f32x2 va = __builtin_amdgcn_cvt_pk_f32_fp8((int)pcw[p], false);
      f32x2 vb = __builtin_amdgcn_cvt_pk_f32_fp8((int)pcw[p], true);
      h16x2 s0 = prb2[p * 2] + pkrtz(va[0], va[1]);
      h16x2 s1 = prb2[p * 2 + 1] + pkrtz(vb[0], vb[1]);
      s0 = __builtin_elementwise_fma(el2, Ej2[p * 2], s0);
      s1 = __builtin_elementwise_fma(el2, Ej2[p * 2 + 1], s1);
      s0 = __builtin_elementwise_max(s0, zero2);
      s1 = __builtin_elementwise_max(s1, zero2);
      tsum = __builtin_amdgcn_fdot2(__builtin_bit_cast(hh2, s0),
                                    __builtin_bit_cast(hh2, a2v2[p * 2]), tsum, false);
      tsum = __builtin_amdgcn_fdot2(__builtin_bit_cast(hh2, s1),
                                    __builtin_bit_cast(hh2, a2v2[p * 2 + 1]), tsum, false);
    }

    tsum = dpp_sum8(tsum);

    float e1f = tsum + ab2v;             // log2 units
    e1f = fmaxf(e1f, 0.2f * e1f);        // leaky relu
    float w = exp2f(e1f);                // global max-shift cancels in the ratio
    w = (e0 < deg) ? w : 0.f;

    const u32* fw = (const u32*)&f4;
#pragma unroll
    for (int p = 0; p < 4; ++p) {
      acc[p * 2]     = fmaf(w, __uint_as_float(fw[p] << 16), acc[p * 2]);
      acc[p * 2 + 1] = fmaf(w, __uint_as_float(fw[p] & 0xffff0000u), acc[p * 2 + 1]);
    }
    wsum += w;
  }

  // merge the 8 groups' partials (once)
#pragma unroll
  for (int sh = 8; sh <= 32; sh <<= 1) {
#pragma unroll
    for (int q = 0; q < 8; ++q) acc[q] += __shfl_xor(acc[q], sh);
    wsum += __shfl_xor(wsum, sh);
  }
  if (g == 0) {
    float inv = 1.0f / (wsum + 1e-10f);
    float* o = out + (size_t)r * (NHEADS * OUT_DIM) + h * OUT_DIM + m * 8;
    *(float4*)o = make_float4(acc[0] * inv, acc[1] * inv, acc[2] * inv, acc[3] * inv);
    *(float4*)(o + 4) = make_float4(acc[4] * inv, acc[5] * inv, acc[6] * inv, acc[7] * inv);
  }
}

extern "C" void kernel_launch(void* const* d_in, const int* in_sizes, int n_in,
                              void* d_out, int out_size, void* d_ws, size_t ws_size,
                              hipStream_t stream) {
  const float* x    = (const float*)d_in[0];
  const int*   idx  = (const int*)d_in[1];
  const float* elem = (const float*)d_in[2];
  const float* W1   = (const float*)d_in[3];
  const float* b1   = (const float*)d_in[4];
  const float* W2   = (const float*)d_in[5];
  const float* b2   = (const float*)d_in[6];
  const float* A1   = (const float*)d_in[7];
  const float* ab1  = (const float*)d_in[8];
  const float* A2   = (const float*)d_in[9];
  const float* ab2  = (const float*)d_in[10];
  float* out = (float*)d_out;

  // workspace (all disjoint; peak ~91 MB)
  u8*  Pr8 = (u8*)d_ws;                                     // 25.6 MB
  u8*  PF  = Pr8 + (size_t)NHEADS * NNODES * PDIM;          // 51.2 MB
  u16* Prt = (u16*)(PF + (size_t)NNODES * 1024);            // 0.4 MB
  u16* Pct = Prt + (size_t)NHEADS * NNODES;                 // 0.4 MB
  u32* cnt = (u32*)(Pct + (size_t)NHEADS * NNODES);         // 0.2 MB
  u32* ce  = cnt + NNODES;                                  // 12.8 MB
  u16* W1T  = (u16*)(ce + (size_t)NNODES * MAXD);           // 0.5 MB
  u16* W2T  = W1T + NHEADS * 256 * 256;
  u16* A1Tr = W2T + NHEADS * 64 * 256;
  u16* A1Tc = A1Tr + NHEADS * PJROWS * 64;
  uint4* thE  = (uint4*)(A1Tc + NHEADS * PJROWS * 64);
  uint4* thA2 = thE + NHEADS * 16;
  float4* th_tail = (float4*)(thA2 + NHEADS * 16);

  (void)hipMemsetAsync(cnt, 0, (size_t)NNODES * sizeof(u32), stream);

  prep_kernel<<<(NEDGES + 255) / 256, 256, 0, stream>>>(
      idx, elem, W1, W2, A1, ab1, A2, ab2, W1T, W2T, A1Tr, A1Tc,
      thE, thA2, th_tail, cnt, ce);

  dim3 gridM((NNODES + 63) / 64, 2);
  mlp_mfma_kernel<<<gridM, 512, 0, stream>>>(x, W1T, b1, W2T, b2, A1Tr, A1Tc,
                                             ab1, PF, Pr8, Prt, Pct);

  edge_csr_kernel<<<NNODES, 256, 0, stream>>>(PF, Pr8, Prt, Pct, cnt, ce,
                                              thE, thA2, th_tail, out);
}

// Round 27
// 300.687 us; speedup vs baseline: 1.1182x; 1.1182x over previous
//
#include <hip/hip_runtime.h>
#include <hip/hip_bf16.h>

#define NNODES 50000
#define NEDGES 800000
#define IN_DIM 256
#define HID_DIM 256
#define OUT_DIM 64
#define NHEADS 4
#define ATT_DIM 129
#define PDIM 128   // main P row length; j=128 tail in separate arrays
#define PJROWS 144 // A1T padded rows (129 -> 144, zero-filled)
#define MAXD 64    // padded CSR slots per row (P(deg>64) ~ 1e-13, clamped)

#define XS_LD 264  // LDS row stride (u16); 528B: %16==0
#define FS_LD 72   // LDS row stride (u16) for 64-wide feats tile; 144B = 9*16
#define PS_LD 144  // LDS row stride (bytes) for fp8 P tiles; 144 = 9*16

#define LOG2E 1.44269504088896340736f

typedef unsigned short u16;
typedef unsigned char u8;
typedef unsigned int u32;
typedef __attribute__((ext_vector_type(8))) short bf16x8;
typedef __attribute__((ext_vector_type(4))) float f32x4;
typedef __attribute__((ext_vector_type(2))) float f32x2;
typedef __attribute__((ext_vector_type(2))) _Float16 h16x2;
typedef __fp16 hh2 __attribute__((ext_vector_type(2)));

__device__ __forceinline__ u16 f2bf(float f) {
  union { __hip_bfloat16 b; u16 u; } v;
  v.b = __float2bfloat16(f);
  return v.u;
}
__device__ __forceinline__ float bf2f(u16 b) {
  return __uint_as_float(((u32)b) << 16);
}
__device__ __forceinline__ h16x2 u2h2(u32 u) {
  union { u32 u; h16x2 h; } v; v.u = u; return v.h;
}
__device__ __forceinline__ u32 h2u(h16x2 h) {
  union { h16x2 h; u32 u; } v; v.h = h; return v.u;
}
__device__ __forceinline__ h16x2 pkrtz(float a, float b) {
  return __builtin_bit_cast(h16x2, __builtin_amdgcn_cvt_pkrtz(a, b));
}
__device__ __forceinline__ u32 cvt_pk_bf16(float a, float b) {
  u32 r;
  asm("v_cvt_pk_bf16_f32 %0, %1, %2" : "=v"(r) : "v"(a), "v"(b));
  return r;
}

// 8-lane xor-sum via DPP: xor1 (quad_perm 0xB1), xor2 (quad_perm 0x4E), then
// half-row mirror (0x141).
__device__ __forceinline__ float dpp_sum8(float x) {
  int v;
  v = __builtin_amdgcn_update_dpp(0, __float_as_int(x), 0xB1, 0xF, 0xF, true);
  x += __int_as_float(v);
  v = __builtin_amdgcn_update_dpp(0, __float_as_int(x), 0x4E, 0xF, 0xF, true);
  x += __int_as_float(v);
  v = __builtin_amdgcn_update_dpp(0, __float_as_int(x), 0x141, 0xF, 0xF, true);
  x += __int_as_float(v);
  return x;
}

// ---------------------------------------------------------------------------
// prep: weight transposes, edge const tables, padded-CSR fill. (r22 version)
// ---------------------------------------------------------------------------
__global__ __launch_bounds__(256) void prep_kernel(
    const int* __restrict__ idx, const float* __restrict__ elem,
    const float* __restrict__ W1, const float* __restrict__ W2,
    const float* __restrict__ A1, const float* __restrict__ ab1,
    const float* __restrict__ A2, const float* __restrict__ ab2,
    u16* __restrict__ W1T, u16* __restrict__ W2T,
    u16* __restrict__ A1Tr, u16* __restrict__ A1Tc,
    uint4* __restrict__ thE, uint4* __restrict__ thA2, uint4* __restrict__ thB1,
    float4* __restrict__ th_tail, u32* __restrict__ cnt, u32* __restrict__ ce)
{
  int id = blockIdx.x * 256 + threadIdx.x;
  if (id < NEDGES) {  // CSR fill
    int r = idx[id];
    u32 p = atomicAdd(&cnt[r], 1u);
    if (p < MAXD)
      ce[r * MAXD + p] = ((u32)f2bf(elem[id]) << 16) | (u32)idx[NEDGES + id];
  }
  if (id < NHEADS * 256 * 256) {
    int h = id >> 16, j = (id >> 8) & 255, k = id & 255;
    W1T[id] = f2bf(W1[(size_t)h * 65536 + k * 256 + j]);
  }
  if (id < NHEADS * 64 * 256) {
    int h = id >> 14, d = (id >> 8) & 63, j = id & 255;
    W2T[id] = f2bf(W2[(size_t)h * 16384 + j * 64 + d]);
  }
  if (id < NHEADS * PJROWS * 64) {
    int h = id / (PJROWS * 64);
    int rem = id % (PJROWS * 64);
    int j = rem >> 6, d = rem & 63;
    A1Tr[id] = (j < ATT_DIM) ? f2bf(A1[(size_t)h * 16641 + d * ATT_DIM + j]) : (u16)0;
    A1Tc[id] = (j < ATT_DIM) ? f2bf(A1[(size_t)h * 16641 + (64 + d) * ATT_DIM + j]) : (u16)0;
  }
  if (id < NHEADS * 16) {
    int h = id >> 4, m = id & 15;
    const float* Erow = A1 + (size_t)h * 16641 + (size_t)128 * ATT_DIM;
    uint4 e, a, b;
    u32* ep = (u32*)&e; u32* ap = (u32*)&a; u32* bp = (u32*)&b;
#pragma unroll
    for (int p = 0; p < 4; ++p) {
      int j = m * 8 + 2 * p;
      ep[p] = h2u(pkrtz(Erow[j], Erow[j + 1]));
      ap[p] = h2u(pkrtz(A2[h * ATT_DIM + j] * LOG2E, A2[h * ATT_DIM + j + 1] * LOG2E));
      bp[p] = h2u(pkrtz(ab1[h * ATT_DIM + j], ab1[h * ATT_DIM + j + 1]));
    }
    thE[id] = e; thA2[id] = a; thB1[id] = b;
  }
  if (id < NHEADS) {
    const float* Erow = A1 + (size_t)id * 16641 + (size_t)128 * ATT_DIM;
    th_tail[id] = make_float4(Erow[128], ab1[id * ATT_DIM + 128],
                              A2[id * ATT_DIM + 128] * LOG2E, ab2[id] * LOG2E);
  }
}

// ---------------------------------------------------------------------------
// Fused MFMA node-MLP + projection; 64-node tiles, 2-head loop, 512 threads
// (8 waves; r25 measured win: 16 waves/CU at 2 blk/CU). L1 splits j 8-ways,
// L2 splits (d-group x node-half), proj strides c by 8.
// PF: [n](4h x {128B fp8 Pc | 128B bf16 feats}); Pr8: [h][n][128] fp8.
// ---------------------------------------------------------------------------
__global__ __launch_bounds__(512) void mlp_mfma_kernel(
    const float* __restrict__ x, const u16* __restrict__ W1T,
    const float* __restrict__ b1, const u16* __restrict__ W2T,
    const float* __restrict__ b2, const u16* __restrict__ A1Tr,
    const u16* __restrict__ A1Tc, u8* __restrict__ PF,
    u8* __restrict__ Pr8, u16* __restrict__ Prt, u16* __restrict__ Pct)
{
  __shared__ u16 xs[64 * XS_LD];  // staged x tile (bf16), intact across heads
  __shared__ u16 hs[64 * XS_LD];  // hid tile; freed after L2, reused for P tiles
  __shared__ u16 fs[64 * FS_LD];  // feats tile (row = 144B = 9*16)
  u8* pc_s = (u8*)hs;             // [64][PS_LD] fp8 Pc tile (overlay)
  u8* pr_s = (u8*)hs + 64 * PS_LD;// [64][PS_LD] fp8 Pr tile (overlay)
  const int n0 = blockIdx.x * 64;
  const int t = threadIdx.x;
  const int wv = t >> 6;   // 0..7
  const int l = t & 63;
  const int lr = l & 15;
  const int lq = l >> 4;

  // ---- stage x tile fp32 -> bf16 (once for both heads) ----
#pragma unroll
  for (int q = 0; q < 8; ++q) {
    int fi = q * 512 + t;        // float4 units: 64 rows x 64
    int row = fi >> 6, c4 = fi & 63;
    int n = n0 + row;
    float4 v = make_float4(0.f, 0.f, 0.f, 0.f);
    if (n < NNODES) v = *(const float4*)(x + (size_t)n * IN_DIM + c4 * 4);
    ushort4 o;
    o.x = f2bf(v.x); o.y = f2bf(v.y); o.z = f2bf(v.z); o.w = f2bf(v.w);
    *(ushort4*)&xs[row * XS_LD + c4 * 4] = o;
  }
  __syncthreads();

  for (int hi = 0; hi < 2; ++hi) {
    const int h = (int)blockIdx.y + hi * 2;

    // ---- layer 1: C[j][node]; wave owns 32 j's (wv*32..+31) ----
    f32x4 acc[2][4];
#pragma unroll
    for (int ji = 0; ji < 2; ++ji)
#pragma unroll
      for (int ni = 0; ni < 4; ++ni) acc[ji][ni] = f32x4{0.f, 0.f, 0.f, 0.f};

    const u16* W1b = W1T + ((size_t)h * 256 + wv * 32) * 256;
#pragma unroll
    for (int kk = 0; kk < 8; ++kk) {
      const int ko = kk * 32 + lq * 8;
      bf16x8 w[2], xv[4];
#pragma unroll
      for (int ji = 0; ji < 2; ++ji)
        w[ji] = *(const bf16x8*)(W1b + (size_t)(ji * 16 + lr) * 256 + ko);
#pragma unroll
      for (int ni = 0; ni < 4; ++ni)
        xv[ni] = *(const bf16x8*)&xs[(ni * 16 + lr) * XS_LD + ko];
#pragma unroll
      for (int ji = 0; ji < 2; ++ji)
#pragma unroll
        for (int ni = 0; ni < 4; ++ni)
          acc[ji][ni] = __builtin_amdgcn_mfma_f32_16x16x32_bf16(w[ji], xv[ni], acc[ji][ni], 0, 0, 0);
    }
#pragma unroll
    for (int ji = 0; ji < 2; ++ji) {
      float4 bv = *(const float4*)(b1 + h * HID_DIM + wv * 32 + ji * 16 + lq * 4);
#pragma unroll
      for (int ni = 0; ni < 4; ++ni) {
        f32x4 v = acc[ji][ni];
        u32 lo = cvt_pk_bf16(fmaxf(v[0] + bv.x, 0.f), fmaxf(v[1] + bv.y, 0.f));
        u32 hi2 = cvt_pk_bf16(fmaxf(v[2] + bv.z, 0.f), fmaxf(v[3] + bv.w, 0.f));
        *(uint2*)&hs[(ni * 16 + lr) * XS_LD + wv * 32 + ji * 16 + lq * 4] = make_uint2(lo, hi2);
      }
    }
    __syncthreads();

    // ---- layer 2: C[d][node]; wave = (d-group wv&3, node-half wv>>2) ----
    {
      const int dg = wv & 3, nh = wv >> 2;
      f32x4 acc2[2];
#pragma unroll
      for (int ni = 0; ni < 2; ++ni) acc2[ni] = f32x4{0.f, 0.f, 0.f, 0.f};
      const u16* W2b = W2T + ((size_t)h * 64 + dg * 16) * 256;
#pragma unroll
      for (int kk = 0; kk < 8; ++kk) {
        const int ko = kk * 32 + lq * 8;
        bf16x8 wd = *(const bf16x8*)(W2b + (size_t)lr * 256 + ko);
#pragma unroll
        for (int ni = 0; ni < 2; ++ni) {
          bf16x8 hv = *(const bf16x8*)&hs[(nh * 32 + ni * 16 + lr) * XS_LD + ko];
          acc2[ni] = __builtin_amdgcn_mfma_f32_16x16x32_bf16(wd, hv, acc2[ni], 0, 0, 0);
        }
      }
      __syncthreads();  // all waves done reading hs (freed for pc_s/pr_s)
      float4 bv = *(const float4*)(b2 + h * OUT_DIM + dg * 16 + lq * 4);
      const int d0 = dg * 16 + lq * 4;
#pragma unroll
      for (int ni = 0; ni < 2; ++ni) {
        f32x4 v = acc2[ni];
        u32 lo = cvt_pk_bf16(v[0] + bv.x, v[1] + bv.y);
        u32 hi2 = cvt_pk_bf16(v[2] + bv.z, v[3] + bv.w);
        *(uint2*)&fs[(nh * 32 + ni * 16 + lr) * FS_LD + d0] = make_uint2(lo, hi2);
      }
    }
    __syncthreads();  // fs complete

    // ---- fused projection -> pc_s / pr_s (LDS); tails direct (tiny) ----
    for (int c = wv; c < 18; c += 8) {
      const int rc = c / 9;
      const int nf = c % 9;
      const u16* Ab = (rc ? A1Tc : A1Tr) + ((size_t)h * PJROWS + nf * 16) * 64;
      f32x4 acc3[4];
#pragma unroll
      for (int ni = 0; ni < 4; ++ni) acc3[ni] = f32x4{0.f, 0.f, 0.f, 0.f};
#pragma unroll
      for (int kk = 0; kk < 2; ++kk) {
        const int ko = kk * 32 + lq * 8;
        bf16x8 aj = *(const bf16x8*)(Ab + (size_t)lr * 64 + ko);
#pragma unroll
        for (int ni = 0; ni < 4; ++ni) {
          bf16x8 fv = *(const bf16x8*)&fs[(ni * 16 + lr) * FS_LD + ko];
          acc3[ni] = __builtin_amdgcn_mfma_f32_16x16x32_bf16(aj, fv, acc3[ni], 0, 0, 0);
        }
      }
#pragma unroll
      for (int ni = 0; ni < 4; ++ni) {
        const int node = ni * 16 + lr;
        int n = n0 + node;
        if (n >= NNODES) continue;
        if (nf == 8) {
          if (lq == 0) {  // j = 128 tail (bf16)
            u16 vb = f2bf(acc3[ni][0]);
            if (rc == 0) Prt[(size_t)h * NNODES + n] = vb;
            else         Pct[(size_t)n * NHEADS + h] = vb;
          }
        } else {
          const int j0 = nf * 16 + lq * 4;
          f32x4 v = acc3[ni];
          u32 pk = __builtin_amdgcn_cvt_pk_fp8_f32(v[0], v[1], 0, false);
          pk = __builtin_amdgcn_cvt_pk_fp8_f32(v[2], v[3], pk, true);
          if (rc == 0) *(u32*)(pr_s + node * PS_LD + j0) = pk;
          else         *(u32*)(pc_s + node * PS_LD + j0) = pk;
        }
      }
    }
    __syncthreads();  // P tiles complete

    // ---- coalesced store phase ----
    // PF: 64 nodes x 16 uint4 (256B contiguous per node = 2 full lines)
#pragma unroll
    for (int it = 0; it < 2; ++it) {
      int flat = it * 512 + t;
      int node = flat >> 4, sub = flat & 15;
      int n = n0 + node;
      if (n < NNODES) {
        uint4 v;
        if (sub < 8) v = *(const uint4*)(pc_s + node * PS_LD + sub * 16);
        else         v = *(const uint4*)((const u8*)&fs[node * FS_LD] + (sub - 8) * 16);
        *(uint4*)(PF + (size_t)n * 1024 + h * 256 + sub * 16) = v;
      }
    }
    // Pr8 tile: [h][n0..n0+64)[128] is one contiguous 8KB run (512 uint4)
    {
      int node = t >> 3, sub = t & 7;
      int n = n0 + node;
      if (n < NNODES) {
        uint4 v = *(const uint4*)(pr_s + node * PS_LD + sub * 16);
        *(uint4*)(Pr8 + ((size_t)h * NNODES + n) * PDIM + sub * 16) = v;
      }
    }
    __syncthreads();  // protect hs/fs reuse by next head
  }
}

// ---------------------------------------------------------------------------
// CSR edge aggregation (r22 version — MEASURED BEST): one (row, head) per
// wave; 8 groups of 8 lanes, 8 edges/iter; lane m covers j=16m..16m+15
// (uint4 fp8 Pc) and output dims 8m..8m+7 (uint4 bf16 feats). 3-level DPP
// reduce.
// ---------------------------------------------------------------------------
__global__ __launch_bounds__(256) void edge_csr_kernel(
    const u8* __restrict__ PF, const u8* __restrict__ Pr8,
    const u16* __restrict__ Prt, const u16* __restrict__ Pct,
    const u32* __restrict__ cnt, const u32* __restrict__ ce,
    const uint4* __restrict__ thE, const uint4* __restrict__ thA2,
    const uint4* __restrict__ thB1, const float4* __restrict__ th_tail,
    float* __restrict__ out)
{
  const int r = blockIdx.x;
  const int h = threadIdx.x >> 6;
  const int l = threadIdx.x & 63;
  const int g = l >> 3;    // 8 groups, edge slot
  const int m = l & 7;     // lane-in-group: j = 16m..16m+15, dims 8m..8m+7

  const int deg = min((int)cnt[r], MAXD);
  if (deg == 0) {  // ref: pooled 0 / (0 + 1e-10) = 0
    if (g == 0) {
      float4 z = make_float4(0.f, 0.f, 0.f, 0.f);
      float* o = out + (size_t)r * (NHEADS * OUT_DIM) + h * OUT_DIM + m * 8;
      *(float4*)o = z; *(float4*)(o + 4) = z;
    }
    return;
  }

  // packed per-lane constants for j = 16m..16m+15 (Pr8 fp8-decoded + ab1)
  h16x2 Ej2[8], a2v2[8], prb2[8];
  {
    uint4 pr8v = *(const uint4*)(Pr8 + ((size_t)h * NNODES + r) * PDIM + m * 16);
    const u32* pw = (const u32*)&pr8v;
#pragma unroll
    for (int half = 0; half < 2; ++half) {
      uint4 Eu = thE[h * 16 + 2 * m + half];
      uint4 Au = thA2[h * 16 + 2 * m + half];
      uint4 Bu = thB1[h * 16 + 2 * m + half];
      const u32* ep = (const u32*)&Eu;
      const u32* ap = (const u32*)&Au;
      const u32* bp = (const u32*)&Bu;
#pragma unroll
      for (int p = 0; p < 2; ++p) {
        u32 w8 = pw[half * 2 + p];
        f32x2 qa = __builtin_amdgcn_cvt_pk_f32_fp8((int)w8, false);
        f32x2 qb = __builtin_amdgcn_cvt_pk_f32_fp8((int)w8, true);
        int o = half * 4 + p * 2;
        Ej2[o]      = u2h2(ep[p * 2]);
        Ej2[o + 1]  = u2h2(ep[p * 2 + 1]);
        a2v2[o]     = u2h2(ap[p * 2]);
        a2v2[o + 1] = u2h2(ap[p * 2 + 1]);
        prb2[o]     = pkrtz(qa[0], qa[1]) + u2h2(bp[p * 2]);
        prb2[o + 1] = pkrtz(qb[0], qb[1]) + u2h2(bp[p * 2 + 1]);
      }
    }
  }
  const float4 tl = th_tail[h];
  float Et = 0.f, prtb = 0.f, a2t = 0.f;
  if (m == 0) {
    Et = tl.x;
    prtb = bf2f(Prt[(size_t)h * NNODES + r]) + tl.y;
    a2t = tl.z;
  }
  const float ab2v = tl.w;
  const h16x2 zero2 = {(_Float16)0.f, (_Float16)0.f};
  const u8* PFh = PF + h * 256;

  const u32* cebase = ce + r * MAXD;

  float acc[8];
#pragma unroll
  for (int q = 0; q < 8; ++q) acc[q] = 0.f;
  float wsum = 0.f;

  for (int k0 = 0; k0 < deg; k0 += 8) {
    const int e0 = k0 + g;
    u32 cv = cebase[(e0 < deg) ? e0 : (deg - 1)];
    u32 coloff = (cv & 0xffffu) << 10;
    float el = __uint_as_float(cv & 0xffff0000u);

    uint4 pc = *(const uint4*)(PFh + coloff + m * 16);        // 16 fp8 Pc
    uint4 f4 = *(const uint4*)(PFh + coloff + 128 + m * 16);  // 8 bf16 feats
    float pctv = (m == 0) ? bf2f(Pct[(coloff >> 8) + h]) : 0.f;

    // tail j=128 (only m==0 lanes have nonzero constants)
    float tsum = fmaxf(fmaf(el, Et, prtb + pctv), 0.f) * a2t;

    const u32* pcw = (const u32*)&pc;
    const h16x2 el2 = pkrtz(el, el);
#pragma unroll
    for (int p = 0; p < 4; ++p) {
      f32x2 va = __builtin_amdgcn_cvt_pk_f32_fp8((int)pcw[p], false);
      f32x2 vb = __builtin_amdgcn_cvt_pk_f32_fp8((int)pcw[p], true);
      h16x2 s0 = prb2[p * 2] + pkrtz(va[0], va[1]);
      h16x2 s1 = prb2[p * 2 + 1] + pkrtz(vb[0], vb[1]);
      s0 = __builtin_elementwise_fma(el2, Ej2[p * 2], s0);
      s1 = __builtin_elementwise_fma(el2, Ej2[p * 2 + 1], s1);
      s0 = __builtin_elementwise_max(s0, zero2);
      s1 = __builtin_elementwise_max(s1, zero2);
      tsum = __builtin_amdgcn_fdot2(__builtin_bit_cast(hh2, s0),
                                    __builtin_bit_cast(hh2, a2v2[p * 2]), tsum, false);
      tsum = __builtin_amdgcn_fdot2(__builtin_bit_cast(hh2, s1),
                                    __builtin_bit_cast(hh2, a2v2[p * 2 + 1]), tsum, false);
    }

    tsum = dpp_sum8(tsum);

    float e1f = tsum + ab2v;             // log2 units
    e1f = fmaxf(e1f, 0.2f * e1f);        // leaky relu
    float w = exp2f(e1f);                // global max-shift cancels in the ratio
    w = (e0 < deg) ? w : 0.f;

    const u32* fw = (const u32*)&f4;
#pragma unroll
    for (int p = 0; p < 4; ++p) {
      acc[p * 2]     = fmaf(w, __uint_as_float(fw[p] << 16), acc[p * 2]);
      acc[p * 2 + 1] = fmaf(w, __uint_as_float(fw[p] & 0xffff0000u), acc[p * 2 + 1]);
    }
    wsum += w;
  }

  // merge the 8 groups' partials (once)
#pragma unroll
  for (int sh = 8; sh <= 32; sh <<= 1) {
#pragma unroll
    for (int q = 0; q < 8; ++q) acc[q] += __shfl_xor(acc[q], sh);
    wsum += __shfl_xor(wsum, sh);
  }
  if (g == 0) {
    float inv = 1.0f / (wsum + 1e-10f);
    float* o = out + (size_t)r * (NHEADS * OUT_DIM) + h * OUT_DIM + m * 8;
    *(float4*)o = make_float4(acc[0] * inv, acc[1] * inv, acc[2] * inv, acc[3] * inv);
    *(float4*)(o + 4) = make_float4(acc[4] * inv, acc[5] * inv, acc[6] * inv, acc[7] * inv);
  }
}

extern "C" void kernel_launch(void* const* d_in, const int* in_sizes, int n_in,
                              void* d_out, int out_size, void* d_ws, size_t ws_size,
                              hipStream_t stream) {
  const float* x    = (const float*)d_in[0];
  const int*   idx  = (const int*)d_in[1];
  const float* elem = (const float*)d_in[2];
  const float* W1   = (const float*)d_in[3];
  const float* b1   = (const float*)d_in[4];
  const float* W2   = (const float*)d_in[5];
  const float* b2   = (const float*)d_in[6];
  const float* A1   = (const float*)d_in[7];
  const float* ab1  = (const float*)d_in[8];
  const float* A2   = (const float*)d_in[9];
  const float* ab2  = (const float*)d_in[10];
  float* out = (float*)d_out;

  // workspace (all disjoint; peak ~91 MB)
  u8*  Pr8 = (u8*)d_ws;                                     // 25.6 MB
  u8*  PF  = Pr8 + (size_t)NHEADS * NNODES * PDIM;          // 51.2 MB
  u16* Prt = (u16*)(PF + (size_t)NNODES * 1024);            // 0.4 MB
  u16* Pct = Prt + (size_t)NHEADS * NNODES;                 // 0.4 MB
  u32* cnt = (u32*)(Pct + (size_t)NHEADS * NNODES);         // 0.2 MB
  u32* ce  = cnt + NNODES;                                  // 12.8 MB
  u16* W1T  = (u16*)(ce + (size_t)NNODES * MAXD);           // 0.5 MB
  u16* W2T  = W1T + NHEADS * 256 * 256;
  u16* A1Tr = W2T + NHEADS * 64 * 256;
  u16* A1Tc = A1Tr + NHEADS * PJROWS * 64;
  uint4* thE  = (uint4*)(A1Tc + NHEADS * PJROWS * 64);
  uint4* thA2 = thE + NHEADS * 16;
  uint4* thB1 = thA2 + NHEADS * 16;
  float4* th_tail = (float4*)(thB1 + NHEADS * 16);

  (void)hipMemsetAsync(cnt, 0, (size_t)NNODES * sizeof(u32), stream);

  prep_kernel<<<(NEDGES + 255) / 256, 256, 0, stream>>>(
      idx, elem, W1, W2, A1, ab1, A2, ab2, W1T, W2T, A1Tr, A1Tc,
      thE, thA2, thB1, th_tail, cnt, ce);

  dim3 gridM((NNODES + 63) / 64, 2);
  mlp_mfma_kernel<<<gridM, 512, 0, stream>>>(x, W1T, b1, W2T, b2, A1Tr, A1Tc,
                                             PF, Pr8, Prt, Pct);

  edge_csr_kernel<<<NNODES, 256, 0, stream>>>(PF, Pr8, Prt, Pct, cnt, ce,
                                              thE, thA2, thB1, th_tail, out);
}